// Round 5
// baseline (592.056 us; speedup 1.0000x reference)
//
#include <hip/hip_runtime.h>

// Problem constants
constexpr int Bn    = 4;
constexpr int Hn    = 192;
constexpr int Wn    = 192;
constexpr int Cn    = 16;
constexpr int HIDn  = 128;
constexpr int HWn   = Hn * Wn;        // 36864
constexpr int BHWn  = Bn * HWn;       // 147456
constexpr int STEPSn = 10;
constexpr int PADn  = 4;
constexpr int KSn   = 9;
constexpr float EPSf  = 1e-5f;
constexpr float FIREf = 0.5f;

// fused kernel geometry: 64 cols x 2 rows per block, 4 waves (channel quads)
constexpr int VY    = 2;
constexpr int SROWS = VY + 8;         // 10 staged rows
constexpr int SCOLS = 72;             // 64 + 8 halo cols
constexpr int TPXc  = 64 * VY;        // 128 px per block
constexpr int CBLK  = BHWn / TPXc;    // 1152 blocks
constexpr int TPIc  = HWn / TPXc;     // 288 tiles per image

typedef __attribute__((ext_vector_type(8))) short short8;
typedef __attribute__((ext_vector_type(4))) float f32x4;

static __device__ __forceinline__ unsigned f2bfu(float f) {
    union { float f; unsigned u; } v; v.f = f;
    return (v.u + 0x7FFFu + ((v.u >> 16) & 1u)) >> 16;   // RNE
}
static __device__ __forceinline__ short f2bf(float f) { return (short)f2bfu(f); }
static __device__ __forceinline__ unsigned pk2(float a, float b) {
    return f2bfu(a) | (f2bfu(b) << 16);
}
static __device__ __forceinline__ float asf(unsigned u) {
    union { unsigned u; float f; } v; v.u = u; return v.f;
}
static __device__ __forceinline__ int refl(int v, int n) {
    v = v < 0 ? -v : v;
    v = v >= n ? 2 * n - 2 - v : v;
    return v;
}

// ---------------------------------------------------------------------------
// One-time weight prep:
//   wtc[tap][c]   = w_p0[c][tap]                              (81x16 f32)
//   bfrag         = wfc0 as MFMA A-operand frags (o=M, k=K):
//                   bfrag[nt][l][j] = bf16(wfc0[nt*16+(l&15)][(l>>4)*8+j])
//   w1f           = wfc1 as MFMA B-operand frags (o=K, c=N):
//                   w1f[ks][l][j]   = bf16(wfc1[l&15][ks*32+(l>>4)*8+j])
// ---------------------------------------------------------------------------
__global__ void k_prep(const float* __restrict__ wp,    // [16][81]
                       const float* __restrict__ wfc1,  // [16][128]
                       const float* __restrict__ wfc0,  // [128][32]
                       float* __restrict__ wtc,
                       short* __restrict__ bfrag,
                       short* __restrict__ w1f)
{
    int tid = threadIdx.x;
    for (int i = tid; i < KSn * KSn * Cn; i += 256) {
        int t = i / Cn, c = i - t * Cn;
        wtc[i] = wp[c * (KSn * KSn) + t];
    }
    for (int i = tid; i < 8 * 64 * 8; i += 256) {
        int nt = i >> 9;
        int rem = i & 511;
        int l = rem >> 3, j = rem & 7;
        bfrag[i] = f2bf(wfc0[(nt * 16 + (l & 15)) * 32 + (l >> 4) * 8 + j]);
    }
    for (int i = tid; i < 4 * 64 * 8; i += 256) {
        int ks = i >> 9;
        int rem = i & 511;
        int l = rem >> 3, j = rem & 7;
        w1f[i] = f2bf(wfc1[(l & 15) * HIDn + ks * 32 + (l >> 4) * 8 + j]);
    }
}

// ---------------------------------------------------------------------------
// Fused: bf16-staged depthwise 9x9 reflect conv + fc0 MFMA (A=weights,
// B=dxv -> D = h[o][px]) + bf16 h store in [b][p][o] + per-block BN stats.
// ---------------------------------------------------------------------------
__global__ __launch_bounds__(256, 4) void k_fused(
    const float* __restrict__ xin,    // [B][H][W][16]
    const float* __restrict__ wtc,    // [81][16]
    const float* __restrict__ bp,     // [16]
    const short* __restrict__ bfrag,  // [8][64][8]
    const float* __restrict__ bfc0,   // [128]
    unsigned short* __restrict__ hbf, // [B][HW][128] bf16
    float2* __restrict__ part)        // [128][CBLK]
{
    __shared__ __align__(16) char smraw[4 * SROWS * SCOLS * 8];  // 23040 B
    uint2* stg = (uint2*)smraw;                        // [4][10][72] bf16x4
    unsigned* sdx = (unsigned*)smraw;                  // [128][20] u32 (10240 B)
    float2* psum = (float2*)(smraw + TPXc * 20 * 4);   // [4][128]    ( 4096 B)

    int tid  = threadIdx.x;
    int lane = tid & 63;
    int w    = __builtin_amdgcn_readfirstlane(tid >> 6);

    int blk = blockIdx.x;
    int b   = blk / TPIc;
    int t   = blk - b * TPIc;
    int ty  = t / 3;
    int tx  = t - ty * 3;
    int y0  = ty * VY;
    int x0  = tx * 64;

    // ---- stage x tile as bf16 (own quad region -> no barrier needed) ----
    const float4* xb4 = (const float4*)(xin + (size_t)b * HWn * Cn);
    int rrow[SROWS];
#pragma unroll
    for (int ri = 0; ri < SROWS; ++ri)
        rrow[ri] = refl(y0 + ri - PADn, Hn) * (Wn * 4);

    uint2* stw = stg + w * (SROWS * SCOLS);
#pragma unroll
    for (int it = 0; it < 12; ++it) {
        int e = it * 64 + lane;
        if (e < SROWS * SCOLS) {
            int ri  = e / SCOLS;
            int col = e - ri * SCOLS;
            int gc  = refl(x0 + col - PADn, Wn);
            float4 v = xb4[rrow[ri] + gc * 4 + w];
            stw[e] = make_uint2(pk2(v.x, v.y), pk2(v.z, v.w));
        }
    }

    // ---- conv: 2 output rows, quad w; batch 9 taps per row for ILP ----
    const float4* wt4 = (const float4*)wtc;
    float4 bq = ((const float4*)bp)[w];
    float4 a0 = bq, a1 = bq;
    uint2 cen0, cen1;
#pragma unroll
    for (int ri = 0; ri < SROWS; ++ri) {
        uint2 tv[KSn];
#pragma unroll
        for (int dx = 0; dx < KSn; ++dx) tv[dx] = stw[ri * SCOLS + lane + dx];
        if (ri == 4) cen0 = tv[4];
        if (ri == 5) cen1 = tv[4];
#pragma unroll
        for (int dx = 0; dx < KSn; ++dx) {
            float c0 = asf(tv[dx].x << 16), c1 = asf(tv[dx].x & 0xffff0000u);
            float c2 = asf(tv[dx].y << 16), c3 = asf(tv[dx].y & 0xffff0000u);
            if (ri <= 8) {
                float4 q = wt4[(ri * KSn + dx) * 4 + w];          // s_load
                a0.x = fmaf(q.x, c0, a0.x); a0.y = fmaf(q.y, c1, a0.y);
                a0.z = fmaf(q.z, c2, a0.z); a0.w = fmaf(q.w, c3, a0.w);
            }
            if (ri >= 1) {
                float4 q = wt4[((ri - 1) * KSn + dx) * 4 + w];    // s_load
                a1.x = fmaf(q.x, c0, a1.x); a1.y = fmaf(q.y, c1, a1.y);
                a1.z = fmaf(q.z, c2, a1.z); a1.w = fmaf(q.w, c3, a1.w);
            }
        }
    }
    __syncthreads();   // all stg reads done before sdx overwrites

    // ---- dxv -> sdx [px][20 words]: words 0-7 = x(bf16), 8-15 = conv ----
#pragma unroll
    for (int r = 0; r < VY; ++r) {
        int px = r * 64 + lane;
        uint2 cv = r ? cen1 : cen0;
        float4 av = r ? a1 : a0;
        unsigned* row = sdx + px * 20;
        *(uint2*)(row + 2 * w)     = cv;
        *(uint2*)(row + 8 + 2 * w) = make_uint2(pk2(av.x, av.y), pk2(av.z, av.w));
    }
    __syncthreads();

    int l15 = lane & 15;
    int kg  = lane >> 4;

    // B-frags (dxv): lane l15 = px within tile, kg*8+j = k
    short8 Bd[VY];
#pragma unroll
    for (int mt = 0; mt < VY; ++mt) {
        int px = 32 * w + 16 * mt + l15;
        Bd[mt] = *(const short8*)(sdx + px * 20 + kg * 4);
    }
    // A-frags (fc0 weights): lane l15 = o within tile
    short8 Af[8];
    const short8* bgp = (const short8*)bfrag;
#pragma unroll
    for (int nt = 0; nt < 8; ++nt) Af[nt] = bgp[nt * 64 + lane];

    unsigned short* hb = hbf + (size_t)b * HWn * HIDn;
#pragma unroll
    for (int nt = 0; nt < 8; ++nt) {
        float4 bias = ((const float4*)bfc0)[nt * 4 + kg];   // o = 16nt+4kg+r
        float s[4] = {0.f, 0.f, 0.f, 0.f}, q[4] = {0.f, 0.f, 0.f, 0.f};
#pragma unroll
        for (int mt = 0; mt < VY; ++mt) {
            f32x4 c = {bias.x, bias.y, bias.z, bias.w};
            c = __builtin_amdgcn_mfma_f32_16x16x32_bf16(Af[nt], Bd[mt], c, 0, 0, 0);
#pragma unroll
            for (int r = 0; r < 4; ++r) { s[r] += c[r]; q[r] += c[r] * c[r]; }
            int px = 32 * w + 16 * mt + l15;
            int p  = (y0 + (px >> 6)) * Wn + x0 + (px & 63);
            *(uint2*)(hb + (size_t)p * HIDn + nt * 16 + kg * 4) =
                make_uint2(pk2(c[0], c[1]), pk2(c[2], c[3]));
        }
#pragma unroll
        for (int r = 0; r < 4; ++r) {
            float sv = s[r], qv = q[r];
            sv += __shfl_xor(sv, 1, 64);  qv += __shfl_xor(qv, 1, 64);
            sv += __shfl_xor(sv, 2, 64);  qv += __shfl_xor(qv, 2, 64);
            sv += __shfl_xor(sv, 4, 64);  qv += __shfl_xor(qv, 4, 64);
            sv += __shfl_xor(sv, 8, 64);  qv += __shfl_xor(qv, 8, 64);
            if (l15 == 0)
                psum[w * HIDn + nt * 16 + kg * 4 + r] = make_float2(sv, qv);
        }
    }
    __syncthreads();

    if (tid < HIDn) {
        float2 p0 = psum[tid], p1 = psum[HIDn + tid];
        float2 p2 = psum[2 * HIDn + tid], p3 = psum[3 * HIDn + tid];
        part[(size_t)tid * CBLK + blk] =
            make_float2(p0.x + p1.x + p2.x + p3.x, p0.y + p1.y + p2.y + p3.y);
    }
}

// ---------------------------------------------------------------------------
// Combine partials -> (scale, shift) per channel.
// ---------------------------------------------------------------------------
__global__ __launch_bounds__(256) void k_combine(
    const float2* __restrict__ part,  // [128][CBLK]
    const float* __restrict__ gamma,
    const float* __restrict__ beta,
    float2* __restrict__ scsh)        // [128]
{
    int o   = blockIdx.x;
    int tid = threadIdx.x;
    float s = 0.f, q = 0.f;
    for (int i = tid; i < CBLK; i += 256) {
        float2 v = part[(size_t)o * CBLK + i];
        s += v.x; q += v.y;
    }
#pragma unroll
    for (int off = 32; off > 0; off >>= 1) {
        s += __shfl_xor(s, off, 64);
        q += __shfl_xor(q, off, 64);
    }
    __shared__ float rs[4], rq[4];
    int wv = tid >> 6;
    if ((tid & 63) == 0) { rs[wv] = s; rq[wv] = q; }
    __syncthreads();
    if (tid == 0) {
        float S = rs[0] + rs[1] + rs[2] + rs[3];
        float Q = rq[0] + rq[1] + rq[2] + rq[3];
        float mean = S * (1.0f / BHWn);
        float var  = Q * (1.0f / BHWn) - mean * mean;
        float g    = gamma[o] * rsqrtf(var + EPSf);
        scsh[o] = make_float2(g, beta[o] - mean * g);
    }
}

// ---------------------------------------------------------------------------
// Update: BN+ReLU in-register, fc1 via MFMA (A = normalized h, B = wt1),
// masked x update, channel 0 frozen. No LDS, no barriers.
// Wave w handles px tile [pb+16w, pb+16w+16).
// ---------------------------------------------------------------------------
__global__ __launch_bounds__(256) void k_update(
    const float* __restrict__ xin,            // [B][H][W][16]
    const unsigned short* __restrict__ hbf,   // [B][HW][128] bf16
    const float2* __restrict__ scsh,          // [128]
    const short* __restrict__ w1f,            // [4][64][8]
    const float* __restrict__ u,              // [B][HW]
    float* __restrict__ xout)                 // [B][H][W][16]
{
    int tid  = threadIdx.x;
    int lane = tid & 63;
    int w    = __builtin_amdgcn_readfirstlane(tid >> 6);
    int l15  = lane & 15;
    int kg   = lane >> 4;

    int blk = blockIdx.x;
    int b   = blk / (HWn / 64);
    int pb  = (blk - b * (HWn / 64)) * 64;
    int pxa = pb + w * 16 + l15;

    const unsigned short* hp = hbf + ((size_t)b * HWn + pxa) * HIDn + kg * 8;
    const short8* wf  = (const short8*)w1f;
    const float4* sc4 = (const float4*)scsh;

    f32x4 c = {0.f, 0.f, 0.f, 0.f};
#pragma unroll
    for (int ks = 0; ks < 4; ++ks) {
        uint4 hv = *(const uint4*)(hp + ks * 32);
        float4 gA = sc4[ks * 16 + kg * 4 + 0];   // (g,s) pairs for j=0,1
        float4 gB = sc4[ks * 16 + kg * 4 + 1];
        float4 gC = sc4[ks * 16 + kg * 4 + 2];
        float4 gD = sc4[ks * 16 + kg * 4 + 3];
        float n0 = fmaxf(fmaf(asf(hv.x << 16),         gA.x, gA.y), 0.f);
        float n1 = fmaxf(fmaf(asf(hv.x & 0xffff0000u), gA.z, gA.w), 0.f);
        float n2 = fmaxf(fmaf(asf(hv.y << 16),         gB.x, gB.y), 0.f);
        float n3 = fmaxf(fmaf(asf(hv.y & 0xffff0000u), gB.z, gB.w), 0.f);
        float n4 = fmaxf(fmaf(asf(hv.z << 16),         gC.x, gC.y), 0.f);
        float n5 = fmaxf(fmaf(asf(hv.z & 0xffff0000u), gC.z, gC.w), 0.f);
        float n6 = fmaxf(fmaf(asf(hv.w << 16),         gD.x, gD.y), 0.f);
        float n7 = fmaxf(fmaf(asf(hv.w & 0xffff0000u), gD.z, gD.w), 0.f);
        union { uint4 u4; short8 s8; } cv;
        cv.u4 = make_uint4(pk2(n0, n1), pk2(n2, n3), pk2(n4, n5), pk2(n6, n7));
        c = __builtin_amdgcn_mfma_f32_16x16x32_bf16(cv.s8, wf[ks * 64 + lane], c, 0, 0, 0);
    }

    // lane holds d[px = pb+16w+4kg+r][channel = l15]
#pragma unroll
    for (int r = 0; r < 4; ++r) {
        int pxr = pb + w * 16 + kg * 4 + r;
        float uu = u[(size_t)b * HWn + pxr];
        float dm = (uu > FIREf && l15 != 0) ? 1.f : 0.f;  // ch 0 frozen
        size_t xo = ((size_t)b * HWn + pxr) * Cn + l15;
        xout[xo] = fmaf(c[r], dm, xin[xo]);
    }
}

// ---------------------------------------------------------------------------
extern "C" void kernel_launch(void* const* d_in, const int* in_sizes, int n_in,
                              void* d_out, int out_size, void* d_ws, size_t ws_size,
                              hipStream_t stream) {
    const float* x0   = (const float*)d_in[0];
    const float* ru   = (const float*)d_in[1];
    const float* wp   = (const float*)d_in[2];
    const float* bp   = (const float*)d_in[3];
    const float* wfc0 = (const float*)d_in[4];
    const float* bfc0 = (const float*)d_in[5];
    const float* wfc1 = (const float*)d_in[6];
    const float* gm   = (const float*)d_in[7];
    const float* bt   = (const float*)d_in[8];

    float* ws = (float*)d_ws;
    unsigned short* hbf = (unsigned short*)ws;            // 18,874,368 u16
    float* xbuf  = ws + 9437184;                          //  2,359,296 f
    float* wtc   = xbuf + 2359296;                        //  1296 -> pad 1312
    short* bfrag = (short*)(wtc + 1312);                  //  4096 s = 2048 f
    short* w1f   = bfrag + 4096;                          //  2048 s = 1024 f
    float2* part = (float2*)(wtc + 1312 + 2048 + 1024);   //  128*CBLK f2
    float2* scsh = part + (size_t)HIDn * CBLK;            //  128 f2

    k_prep<<<1, 256, 0, stream>>>(wp, wfc1, wfc0, wtc, bfrag, w1f);

    const float* xcur = x0;
    for (int s = 0; s < STEPSn; ++s) {
        k_fused<<<CBLK, 256, 0, stream>>>(xcur, wtc, bp, bfrag, bfc0, hbf, part);
        k_combine<<<HIDn, 256, 0, stream>>>(part, gm, bt, scsh);
        float* xo = (s == STEPSn - 1) ? (float*)d_out : xbuf;
        k_update<<<BHWn / 64, 256, 0, stream>>>(xcur, hbf, scsh, w1f,
                                                ru + (size_t)s * BHWn, xo);
        xcur = xo;
    }
}